// Round 1
// baseline (710.913 us; speedup 1.0000x reference)
//
#include <hip/hip_runtime.h>
#include <stdint.h>

// out[b, q, n] = softmax_n( fact * S[b, q*8+n] ),  S[b,o] = sum_c ql[c,b,o]*kl[c,o]
//   ql[c,b,o] = sum_h q[c,b,h]*Wq[o,h] + bq[o]
//   kl[c,o]   = sum_d k[c,d]*Wk[o,d] + bk[o]
// A=B=256, H=QD=2048, n=8, fact = 1/16.
//
// R(this): convert now TRANSPOSES q to [b][c][h] bf16 so main_kernel's A-panel
// is a contiguous 1 MB block per b (m201-identical access pattern). Fixes the
// L3 thrash (FETCH 1.09 GB -> ~0.3 GB) that stalled MFMA at the vmcnt waits.

typedef __attribute__((ext_vector_type(8))) __bf16 bf16x8;
typedef __attribute__((ext_vector_type(4))) __bf16 bf16x4;
typedef __attribute__((ext_vector_type(4))) float f32x4;

__device__ __forceinline__ void gload_lds16(const void* g, void* l) {
  __builtin_amdgcn_global_load_lds(
      (const __attribute__((address_space(1))) uint32_t*)g,
      (__attribute__((address_space(3))) uint32_t*)l, 16, 0, 0);
}

// ---------------- convert: q (f32, transpose to [b][c][h]), Wq, Wk, k -> bf16
__global__ void convert_kernel(const float* __restrict__ qin,
                               const float* __restrict__ Wq,
                               const float* __restrict__ Wk,
                               const float* __restrict__ kin,
                               void* __restrict__ q_t,
                               void* __restrict__ wq_b, void* __restrict__ wk_b,
                               void* __restrict__ k_b) {
  const int NQ0 = 33554432;  // q float4 quads (256*256*2048/4); 512 quads/row
  const int NQ1 = 1048576;   // Wq quads
  const int NQ2 = 1048576;   // Wk quads
  const int NQ3 = 131072;    // k quads
  const int TOT = NQ0 + NQ1 + NQ2 + NQ3;
  for (int i = blockIdx.x * blockDim.x + threadIdx.x; i < TOT;
       i += gridDim.x * blockDim.x) {
    if (i < NQ0) {
      // src quad i = ((c*256)+b)*512 + jq  ->  dst quad = ((b*256)+c)*512 + jq
      float4 v = ((const float4*)qin)[i];
      const int jq = i & 511;
      const int b  = (i >> 9) & 255;
      const int c  = i >> 17;
      bf16x4 o;
      o[0] = (__bf16)v.x; o[1] = (__bf16)v.y; o[2] = (__bf16)v.z; o[3] = (__bf16)v.w;
      ((bf16x4*)q_t)[(int64_t)(((b << 8) + c) << 9) + jq] = o;
    } else {
      const float4* src; bf16x4* dst; int j;
      if (i < NQ0+NQ1)              { src = (const float4*)Wq;  dst = (bf16x4*)wq_b; j = i - NQ0; }
      else if (i < NQ0+NQ1+NQ2)     { src = (const float4*)Wk;  dst = (bf16x4*)wk_b; j = i - NQ0 - NQ1; }
      else                          { src = (const float4*)kin; dst = (bf16x4*)k_b;  j = i - NQ0 - NQ1 - NQ2; }
      float4 v = src[j];
      bf16x4 o;
      o[0] = (__bf16)v.x; o[1] = (__bf16)v.y; o[2] = (__bf16)v.z; o[3] = (__bf16)v.w;
      dst[j] = o;
    }
  }
}

// ---------------- kl kernel: kl_t[o][c] = bf16(k . Wk^T + bk) ----------------
__global__ __launch_bounds__(256)
void kl_kernel(const void* __restrict__ k_b, const void* __restrict__ wk_b,
               const float* __restrict__ bk, void* __restrict__ kl_t_v) {
  __shared__ char smem[32768];  // 2 bufs x (A 8K + B 8K)
  const __bf16* kb   = (const __bf16*)k_b;
  const __bf16* wkb  = (const __bf16*)wk_b;
  __bf16* kl_t = (__bf16*)kl_t_v;
  const int t = threadIdx.x, w = t >> 6, l = t & 63;
  const int ntile = blockIdx.x, mtile = blockIdx.y;
  const int wr = w >> 1, wc = w & 1;
  f32x4 acc[2][2] = {};

  auto stage = [&](int buf, int kt) {
    const int row = t >> 3;
    const int col = (((t & 7) ^ (row & 7)) << 3);
#pragma unroll
    for (int i = 0; i < 2; ++i) {
      const __bf16* ga = kb + (int64_t)(mtile*64 + i*32 + row) * 2048 + kt*64 + col;
      gload_lds16(ga, smem + buf*16384 + (i*256 + w*64)*16);
      const __bf16* gb = wkb + (int64_t)(ntile*64 + i*32 + row) * 2048 + kt*64 + col;
      gload_lds16(gb, smem + buf*16384 + 8192 + (i*256 + w*64)*16);
    }
  };

  stage(0, 0);
  __syncthreads();
  int cur = 0;
  for (int kt = 0; kt < 32; ++kt) {
    if (kt + 1 < 32) stage(cur ^ 1, kt + 1);
    const char* bA = smem + cur*16384;
    const char* bB = smem + cur*16384 + 8192;
#pragma unroll
    for (int kq = 0; kq < 2; ++kq) {
      bf16x8 a[2], b[2];
      const int g = kq*4 + (l >> 4);
#pragma unroll
      for (int mi = 0; mi < 2; ++mi) {
        const int r = wr*32 + mi*16 + (l & 15);
        a[mi] = *(const bf16x8*)(bA + r*128 + ((g ^ (r & 7)) << 4));
      }
#pragma unroll
      for (int ni = 0; ni < 2; ++ni) {
        const int r = wc*32 + ni*16 + (l & 15);
        b[ni] = *(const bf16x8*)(bB + r*128 + ((g ^ (r & 7)) << 4));
      }
#pragma unroll
      for (int mi = 0; mi < 2; ++mi)
#pragma unroll
        for (int ni = 0; ni < 2; ++ni)
          acc[mi][ni] = __builtin_amdgcn_mfma_f32_16x16x32_bf16(a[mi], b[ni], acc[mi][ni], 0, 0, 0);
    }
    __syncthreads();
    cur ^= 1;
  }

#pragma unroll
  for (int ni = 0; ni < 2; ++ni) {
    const int o = ntile*64 + wc*32 + ni*16 + (l & 15);
    const float bko = bk[o];
#pragma unroll
    for (int mi = 0; mi < 2; ++mi) {
      const int c0 = mtile*64 + wr*32 + mi*16 + (l >> 4)*4;
      bf16x4 v;
      v[0] = (__bf16)(acc[mi][ni][0] + bko);
      v[1] = (__bf16)(acc[mi][ni][1] + bko);
      v[2] = (__bf16)(acc[mi][ni][2] + bko);
      v[3] = (__bf16)(acc[mi][ni][3] + bko);
      *(bf16x4*)(kl_t + (int64_t)o*256 + c0) = v;
    }
  }
}

// ---------------- main fused kernel (faithful m201 8-phase schedule) --------
// 256x256 tile, BK=64, 8 waves (2M x 4N), R2's 0-conflict LDS layout.
// Phase = one C-quadrant (qm,qn) x K=64: 12 ds_read_b128 + 16 MFMA.
// 8 phases cover 2 K-tiles; 1 half-tile (2 gloads/thread) staged per phase,
// placed where the target region is provably dead; vmcnt(4) only at phases
// 4 and 8 (2 half-tiles stay in flight); no drains in the loop.
#define PHASE(BUF, QM, QN, STAGE_STMT, VM_STMT) do {                          \
  const char* bA_ = smem + (BUF)*32768;                                       \
  const char* bB_ = smem + 65536 + (BUF)*32768;                               \
  bf16x8 afx0[4], afx1[4], bfx0[2], bfx1[2];                                  \
  {                                                                           \
    const int lg_ = l >> 4;                                                   \
    _Pragma("unroll") for (int j2 = 0; j2 < 4; ++j2) {                        \
      const int r_ = wr*128 + ((QM)*4 + j2)*16 + (l & 15);                    \
      afx0[j2] = *(const bf16x8*)(bA_ + r_*128 + ((lg_ ^ (r_ & 7)) << 4));    \
      afx1[j2] = *(const bf16x8*)(bA_ + r_*128 + (((4+lg_) ^ (r_ & 7)) << 4));\
    }                                                                         \
    _Pragma("unroll") for (int n2 = 0; n2 < 2; ++n2) {                        \
      const int r_ = wc*64 + ((QN)*2 + n2)*16 + (l & 15);                     \
      bfx0[n2] = *(const bf16x8*)(bB_ + r_*128 + ((lg_ ^ (r_ & 7)) << 4));    \
      bfx1[n2] = *(const bf16x8*)(bB_ + r_*128 + (((4+lg_) ^ (r_ & 7)) << 4));\
    }                                                                         \
  }                                                                           \
  STAGE_STMT;                                                                 \
  asm volatile("s_waitcnt lgkmcnt(8)" ::: "memory");                          \
  __builtin_amdgcn_s_barrier();                                               \
  asm volatile("s_waitcnt lgkmcnt(0)" ::: "memory");                          \
  __builtin_amdgcn_sched_barrier(0);                                          \
  __builtin_amdgcn_s_setprio(1);                                              \
  _Pragma("unroll") for (int j2 = 0; j2 < 4; ++j2)                            \
    _Pragma("unroll") for (int n2 = 0; n2 < 2; ++n2)                          \
      acc[(QM)*4+j2][(QN)*2+n2] = __builtin_amdgcn_mfma_f32_16x16x32_bf16(    \
          afx0[j2], bfx0[n2], acc[(QM)*4+j2][(QN)*2+n2], 0, 0, 0);            \
  _Pragma("unroll") for (int j2 = 0; j2 < 4; ++j2)                            \
    _Pragma("unroll") for (int n2 = 0; n2 < 2; ++n2)                          \
      acc[(QM)*4+j2][(QN)*2+n2] = __builtin_amdgcn_mfma_f32_16x16x32_bf16(    \
          afx1[j2], bfx1[n2], acc[(QM)*4+j2][(QN)*2+n2], 0, 0, 0);            \
  __builtin_amdgcn_s_setprio(0);                                              \
  VM_STMT;                                                                    \
  __builtin_amdgcn_s_barrier();                                               \
} while (0)

__global__ __launch_bounds__(512, 2)
void main_kernel(const void* __restrict__ q_tv, const void* __restrict__ wq_b,
                 const float* __restrict__ bq, const void* __restrict__ kl_t_v,
                 float* __restrict__ out) {
  __shared__ char smem[131072];  // A: [0,64K) 2 bufs x 32K; B: [64K,128K)
  const __bf16* qt   = (const __bf16*)q_tv;   // [b][c][h] bf16
  const __bf16* wqb  = (const __bf16*)wq_b;
  const __bf16* kl_t = (const __bf16*)kl_t_v;
  const int t = threadIdx.x, w = t >> 6, l = t & 63;
  const int otile = blockIdx.x, b = blockIdx.y;
  const int wr = w >> 2, wc = w & 3;
  f32x4 acc[8][4] = {};

  // stage A-stripe qm of tile kt (rows qm*64+[0,64) and 128+qm*64+[0,64))
  // A-panel for this b is CONTIGUOUS: qt + b*256*2048, row r = c.
  auto stageA = [&](int buf, int kt, int qm) {
#pragma unroll
    for (int i = 0; i < 2; ++i) {
      const int r = i*128 + qm*64 + (t >> 3);
      const int sg = (t & 7) ^ (r & 7);
      const __bf16* ga = qt + (int64_t)(b*256 + r) * 2048 + kt*64 + sg*8;
      gload_lds16(ga, smem + buf*32768 + r*128 + (t & 7)*16);
    }
  };
  // stage B-stripe qn of tile kt (rows with (o mod 64) in [qn*32, qn*32+32))
  auto stageB = [&](int buf, int kt, int qn) {
#pragma unroll
    for (int i = 0; i < 2; ++i) {
      const int row64 = t >> 3;
      const int r = i*128 + qn*32 + (row64 & 31) + ((row64 >> 5) << 6);
      const int sg = (t & 7) ^ (r & 7);
      const __bf16* gb = wqb + (int64_t)(otile*256 + r) * 2048 + kt*64 + sg*8;
      gload_lds16(gb, smem + 65536 + buf*32768 + r*128 + (t & 7)*16);
    }
  };

  // prologue: t0 full (8 loads) + t1 A0,B0 (4 loads); vmcnt(4) -> t0 done
  stageA(0, 0, 0); stageA(0, 0, 1); stageB(0, 0, 0); stageB(0, 0, 1);
  stageA(1, 1, 0); stageB(1, 1, 0);
  asm volatile("s_waitcnt vmcnt(4)" ::: "memory");
  __builtin_amdgcn_s_barrier();

  for (int j = 0; j < 16; ++j) {
    const int kt0 = 2*j, kt1 = 2*j + 1;
    const bool p2 = (j < 15);
    PHASE(0, 0, 0, { stageA(1, kt1, 1); }, {});
    PHASE(0, 0, 1, { stageB(1, kt1, 1); }, {});
    PHASE(0, 1, 0, { if (p2) stageA(0, kt0+2, 0); }, {});
    PHASE(0, 1, 1, { if (p2) stageB(0, kt0+2, 0); },
          { if (p2) { asm volatile("s_waitcnt vmcnt(4)" ::: "memory"); }
            else    { asm volatile("s_waitcnt vmcnt(0)" ::: "memory"); } });
    PHASE(1, 0, 0, { if (p2) stageA(0, kt0+2, 1); }, {});
    PHASE(1, 0, 1, { if (p2) stageB(0, kt0+2, 1); }, {});
    PHASE(1, 1, 0, { if (p2) stageA(1, kt1+2, 0); }, {});
    PHASE(1, 1, 1, { if (p2) stageB(1, kt1+2, 0); },
          { if (p2) { asm volatile("s_waitcnt vmcnt(4)" ::: "memory"); } });
  }

  // ---- epilogue ----
  // C/D frag layout: row(c) = wr*128 + mi*16 + (l>>4)*4 + reg, col(o) = wc*64 + ni*16 + (l&15)
  float psum[4] = {0.f, 0.f, 0.f, 0.f};
#pragma unroll
  for (int ni = 0; ni < 4; ++ni) {
    const int o = otile*256 + wc*64 + ni*16 + (l & 15);
    const float bqo = bq[o];
    const __bf16* klc = kl_t + (int64_t)o * 256 + wr*128 + (l >> 4)*4;
#pragma unroll
    for (int mi = 0; mi < 8; ++mi) {
      bf16x4 kv = *(const bf16x4*)(klc + mi*16);
      psum[ni] += (acc[mi][ni][0] + bqo) * (float)kv[0]
                + (acc[mi][ni][1] + bqo) * (float)kv[1]
                + (acc[mi][ni][2] + bqo) * (float)kv[2]
                + (acc[mi][ni][3] + bqo) * (float)kv[3];
    }
  }
#pragma unroll
  for (int ni = 0; ni < 4; ++ni) {  // reduce over the 4 row-groups (l>>4)
    psum[ni] += __shfl_xor(psum[ni], 16);
    psum[ni] += __shfl_xor(psum[ni], 32);
  }
  float* red = (float*)smem;  // [2][256] f32 in buf0 A (last phase used buf1)
  if (l < 16) {
#pragma unroll
    for (int ni = 0; ni < 4; ++ni)
      red[wr*256 + wc*64 + ni*16 + l] = psum[ni];
  }
  __syncthreads();
  if (t < 256) {
    const float s = 0.0625f * (red[t] + red[256 + t]);  // fact * S[b, otile*256+t]
    float m = s;
    m = fmaxf(m, __shfl_xor(m, 1));
    m = fmaxf(m, __shfl_xor(m, 2));
    m = fmaxf(m, __shfl_xor(m, 4));
    const float e = __expf(s - m);
    float sum = e;
    sum += __shfl_xor(sum, 1);
    sum += __shfl_xor(sum, 2);
    sum += __shfl_xor(sum, 4);
    out[(int64_t)b*2048 + otile*256 + t] = e / sum;
  }
}

extern "C" void kernel_launch(void* const* d_in, const int* in_sizes, int n_in,
                              void* d_out, int out_size, void* d_ws, size_t ws_size,
                              hipStream_t stream) {
  (void)in_sizes; (void)n_in; (void)out_size; (void)ws_size;
  const float* q  = (const float*)d_in[0];
  const float* k  = (const float*)d_in[1];
  const float* Wq = (const float*)d_in[2];
  const float* bq = (const float*)d_in[3];
  const float* Wk = (const float*)d_in[4];
  const float* bk = (const float*)d_in[5];
  float* out = (float*)d_out;
  char* ws = (char*)d_ws;
  void* q_t  = ws;                          // 256 MiB  q bf16 TRANSPOSED [b][c][h]
  void* wq_b = ws + 268435456;              // 8 MiB    Wq bf16
  void* wk_b = ws + 268435456 + 8388608;    // 8 MiB    Wk bf16
  void* k_b  = ws + 268435456 + 16777216;   // 1 MiB    k bf16
  void* kl_t = ws + 268435456 + 17825792;   // 1 MiB    kl_t bf16 [2048 o][256 c]

  convert_kernel<<<2048, 256, 0, stream>>>(q, Wq, Wk, k, q_t, wq_b, wk_b, k_b);
  kl_kernel<<<dim3(32, 4), 256, 0, stream>>>(k_b, wk_b, bk, kl_t);
  main_kernel<<<dim3(8, 256), 512, 0, stream>>>(q_t, wq_b, bq, kl_t, out);
}

// Round 2
// 673.526 us; speedup vs baseline: 1.0555x; 1.0555x over previous
//
#include <hip/hip_runtime.h>
#include <stdint.h>

// out[b, q, n] = softmax_n( fact * S[b, q*8+n] ),  S[b,o] = sum_c ql[c,b,o]*kl[c,o]
//   ql[c,b,o] = sum_h q[c,b,h]*Wq[o,h] + bq[o]
//   kl[c,o]   = sum_d k[c,d]*Wk[o,d] + bk[o]
// A=B=256, H=QD=2048, n=8, fact = 1/16.
//
// R2: full-grid phases (32 MFMA per 12 ds_read, 2 phases/K-tile = 64 phases)
// + 3-buffer A / 2-buffer B in 160 KiB LDS. Halves LDS read traffic per FLOP
// and barrier count; A prefetched 2 K-tiles ahead (fence vmcnt(4) never waits
// on same-phase loads). Fragment layout / swizzle / epilogue unchanged.

typedef __attribute__((ext_vector_type(8))) __bf16 bf16x8;
typedef __attribute__((ext_vector_type(4))) __bf16 bf16x4;
typedef __attribute__((ext_vector_type(4))) float f32x4;

__device__ __forceinline__ void gload_lds16(const void* g, void* l) {
  __builtin_amdgcn_global_load_lds(
      (const __attribute__((address_space(1))) uint32_t*)g,
      (__attribute__((address_space(3))) uint32_t*)l, 16, 0, 0);
}

// ---------------- convert: q (f32, transpose to [b][c][h]), Wq, Wk, k -> bf16
__global__ void convert_kernel(const float* __restrict__ qin,
                               const float* __restrict__ Wq,
                               const float* __restrict__ Wk,
                               const float* __restrict__ kin,
                               void* __restrict__ q_t,
                               void* __restrict__ wq_b, void* __restrict__ wk_b,
                               void* __restrict__ k_b) {
  const int NQ0 = 33554432;  // q float4 quads (256*256*2048/4); 512 quads/row
  const int NQ1 = 1048576;   // Wq quads
  const int NQ2 = 1048576;   // Wk quads
  const int NQ3 = 131072;    // k quads
  const int TOT = NQ0 + NQ1 + NQ2 + NQ3;
  for (int i = blockIdx.x * blockDim.x + threadIdx.x; i < TOT;
       i += gridDim.x * blockDim.x) {
    if (i < NQ0) {
      // src quad i = ((c*256)+b)*512 + jq  ->  dst quad = ((b*256)+c)*512 + jq
      float4 v = ((const float4*)qin)[i];
      const int jq = i & 511;
      const int b  = (i >> 9) & 255;
      const int c  = i >> 17;
      bf16x4 o;
      o[0] = (__bf16)v.x; o[1] = (__bf16)v.y; o[2] = (__bf16)v.z; o[3] = (__bf16)v.w;
      ((bf16x4*)q_t)[(int64_t)(((b << 8) + c) << 9) + jq] = o;
    } else {
      const float4* src; bf16x4* dst; int j;
      if (i < NQ0+NQ1)              { src = (const float4*)Wq;  dst = (bf16x4*)wq_b; j = i - NQ0; }
      else if (i < NQ0+NQ1+NQ2)     { src = (const float4*)Wk;  dst = (bf16x4*)wk_b; j = i - NQ0 - NQ1; }
      else                          { src = (const float4*)kin; dst = (bf16x4*)k_b;  j = i - NQ0 - NQ1 - NQ2; }
      float4 v = src[j];
      bf16x4 o;
      o[0] = (__bf16)v.x; o[1] = (__bf16)v.y; o[2] = (__bf16)v.z; o[3] = (__bf16)v.w;
      dst[j] = o;
    }
  }
}

// ---------------- kl kernel: kl_t[o][c] = bf16(k . Wk^T + bk) ----------------
__global__ __launch_bounds__(256)
void kl_kernel(const void* __restrict__ k_b, const void* __restrict__ wk_b,
               const float* __restrict__ bk, void* __restrict__ kl_t_v) {
  __shared__ char smem[32768];  // 2 bufs x (A 8K + B 8K)
  const __bf16* kb   = (const __bf16*)k_b;
  const __bf16* wkb  = (const __bf16*)wk_b;
  __bf16* kl_t = (__bf16*)kl_t_v;
  const int t = threadIdx.x, w = t >> 6, l = t & 63;
  const int ntile = blockIdx.x, mtile = blockIdx.y;
  const int wr = w >> 1, wc = w & 1;
  f32x4 acc[2][2] = {};

  auto stage = [&](int buf, int kt) {
    const int row = t >> 3;
    const int col = (((t & 7) ^ (row & 7)) << 3);
#pragma unroll
    for (int i = 0; i < 2; ++i) {
      const __bf16* ga = kb + (int64_t)(mtile*64 + i*32 + row) * 2048 + kt*64 + col;
      gload_lds16(ga, smem + buf*16384 + (i*256 + w*64)*16);
      const __bf16* gb = wkb + (int64_t)(ntile*64 + i*32 + row) * 2048 + kt*64 + col;
      gload_lds16(gb, smem + buf*16384 + 8192 + (i*256 + w*64)*16);
    }
  };

  stage(0, 0);
  __syncthreads();
  int cur = 0;
  for (int kt = 0; kt < 32; ++kt) {
    if (kt + 1 < 32) stage(cur ^ 1, kt + 1);
    const char* bA = smem + cur*16384;
    const char* bB = smem + cur*16384 + 8192;
#pragma unroll
    for (int kq = 0; kq < 2; ++kq) {
      bf16x8 a[2], b[2];
      const int g = kq*4 + (l >> 4);
#pragma unroll
      for (int mi = 0; mi < 2; ++mi) {
        const int r = wr*32 + mi*16 + (l & 15);
        a[mi] = *(const bf16x8*)(bA + r*128 + ((g ^ (r & 7)) << 4));
      }
#pragma unroll
      for (int ni = 0; ni < 2; ++ni) {
        const int r = wc*32 + ni*16 + (l & 15);
        b[ni] = *(const bf16x8*)(bB + r*128 + ((g ^ (r & 7)) << 4));
      }
#pragma unroll
      for (int mi = 0; mi < 2; ++mi)
#pragma unroll
        for (int ni = 0; ni < 2; ++ni)
          acc[mi][ni] = __builtin_amdgcn_mfma_f32_16x16x32_bf16(a[mi], b[ni], acc[mi][ni], 0, 0, 0);
    }
    __syncthreads();
    cur ^= 1;
  }

#pragma unroll
  for (int ni = 0; ni < 2; ++ni) {
    const int o = ntile*64 + wc*32 + ni*16 + (l & 15);
    const float bko = bk[o];
#pragma unroll
    for (int mi = 0; mi < 2; ++mi) {
      const int c0 = mtile*64 + wr*32 + mi*16 + (l >> 4)*4;
      bf16x4 v;
      v[0] = (__bf16)(acc[mi][ni][0] + bko);
      v[1] = (__bf16)(acc[mi][ni][1] + bko);
      v[2] = (__bf16)(acc[mi][ni][2] + bko);
      v[3] = (__bf16)(acc[mi][ni][3] + bko);
      *(bf16x4*)(kl_t + (int64_t)o*256 + c0) = v;
    }
  }
}

// ---------------- main fused kernel: full-grid phases, 3-buf A / 2-buf B ----
// Phase(H) = all 8x4 accumulator tiles x K=32 (k-half H of the K=64 tile):
//   12 ds_read_b128 (af[8] + bf[4]) feeding 32 MFMA (each bf reused 8x).
// 2 phases per K-tile, 64 phases total. Staging: p0 stages B(kt+1) (both
// halves, L2-resident Wq, 1-tile depth); p1 stages A(kt+2) (2-tile depth)
// and fences vmcnt(4) -> completes A(kt+1)+B(kt+1), leaves A(kt+2) in flight.
#define PHASE2(ABUF, BBUF, H, STAGE_STMT, VM_STMT) do {                       \
  const char* bA_ = smem + (ABUF)*32768;                                      \
  const char* bB_ = smem + 98304 + (BBUF)*32768;                              \
  bf16x8 af[8]; bf16x8 bf[4];                                                 \
  {                                                                           \
    const int g_ = (H)*4 + (l >> 4);                                          \
    _Pragma("unroll") for (int m2 = 0; m2 < 8; ++m2) {                        \
      const int r_ = wr*128 + m2*16 + (l & 15);                               \
      af[m2] = *(const bf16x8*)(bA_ + r_*128 + ((g_ ^ (r_ & 7)) << 4));       \
    }                                                                         \
    _Pragma("unroll") for (int n2 = 0; n2 < 4; ++n2) {                        \
      const int r_ = wc*64 + n2*16 + (l & 15);                                \
      bf[n2] = *(const bf16x8*)(bB_ + r_*128 + ((g_ ^ (r_ & 7)) << 4));       \
    }                                                                         \
  }                                                                           \
  STAGE_STMT;                                                                 \
  asm volatile("s_waitcnt lgkmcnt(8)" ::: "memory");                          \
  __builtin_amdgcn_s_barrier();                                               \
  asm volatile("s_waitcnt lgkmcnt(0)" ::: "memory");                          \
  __builtin_amdgcn_sched_barrier(0);                                          \
  __builtin_amdgcn_s_setprio(1);                                              \
  _Pragma("unroll") for (int m2 = 0; m2 < 8; ++m2)                            \
    _Pragma("unroll") for (int n2 = 0; n2 < 4; ++n2)                          \
      acc[m2][n2] = __builtin_amdgcn_mfma_f32_16x16x32_bf16(                  \
          af[m2], bf[n2], acc[m2][n2], 0, 0, 0);                              \
  __builtin_amdgcn_s_setprio(0);                                              \
  VM_STMT;                                                                    \
  __builtin_amdgcn_s_barrier();                                               \
} while (0)

__global__ __launch_bounds__(512, 2)
void main_kernel(const void* __restrict__ q_tv, const void* __restrict__ wq_b,
                 const float* __restrict__ bq, const void* __restrict__ kl_t_v,
                 float* __restrict__ out) {
  __shared__ char smem[163840];  // A: 3 bufs x 32K [0,96K); B: 2 bufs x 32K [96K,160K)
  const __bf16* qt   = (const __bf16*)q_tv;   // [b][c][h] bf16
  const __bf16* wqb  = (const __bf16*)wq_b;
  const __bf16* kl_t = (const __bf16*)kl_t_v;
  const int t = threadIdx.x, w = t >> 6, l = t & 63;
  const int otile = blockIdx.x, b = blockIdx.y;
  const int wr = w >> 2, wc = w & 3;
  f32x4 acc[8][4] = {};

  // stage A row-half of tile kt (rows half*64+[0,64) and 128+half*64+[0,64))
  auto stageA = [&](int buf, int kt, int half) {
#pragma unroll
    for (int i = 0; i < 2; ++i) {
      const int r = i*128 + half*64 + (t >> 3);
      const int sg = (t & 7) ^ (r & 7);
      const __bf16* ga = qt + (int64_t)(b*256 + r) * 2048 + kt*64 + sg*8;
      gload_lds16(ga, smem + buf*32768 + r*128 + (t & 7)*16);
    }
  };
  // stage B row-half of tile kt
  auto stageB = [&](int buf, int kt, int half) {
#pragma unroll
    for (int i = 0; i < 2; ++i) {
      const int row64 = t >> 3;
      const int r = i*128 + half*32 + (row64 & 31) + ((row64 >> 5) << 6);
      const int sg = (t & 7) ^ (r & 7);
      const __bf16* gb = wqb + (int64_t)(otile*256 + r) * 2048 + kt*64 + sg*8;
      gload_lds16(gb, smem + 98304 + buf*32768 + r*128 + (t & 7)*16);
    }
  };

  // prologue: A(0), B(0) full + A(1) full; vmcnt(4) -> tile0 complete,
  // A(1) (4 loads) stays in flight == steady-state entry condition.
  stageA(0, 0, 0); stageA(0, 0, 1);
  stageB(0, 0, 0); stageB(0, 0, 1);
  stageA(1, 1, 0); stageA(1, 1, 1);
  asm volatile("s_waitcnt vmcnt(4)" ::: "memory");
  __builtin_amdgcn_s_barrier();

  int ac = 0;  // A-buf holding tile kt (= kt % 3)
  for (int kt = 0; kt < 32; ++kt) {
    const int as = (ac >= 1) ? ac - 1 : ac + 2;  // (kt+2) % 3
    const int bc = kt & 1, bs = bc ^ 1;
    const bool sA = (kt < 30), sB = (kt < 31);
    PHASE2(ac, bc, 0,
           { if (sB) { stageB(bs, kt + 1, 0); stageB(bs, kt + 1, 1); } },
           {});
    PHASE2(ac, bc, 1,
           { if (sA) { stageA(as, kt + 2, 0); stageA(as, kt + 2, 1); } },
           { if (sA)      { asm volatile("s_waitcnt vmcnt(4)" ::: "memory"); }
             else if (sB) { asm volatile("s_waitcnt vmcnt(0)" ::: "memory"); } });
    ac = (ac == 2) ? 0 : ac + 1;
  }

  // ---- epilogue ----
  // C/D frag layout: row(c) = wr*128 + mi*16 + (l>>4)*4 + reg, col(o) = wc*64 + ni*16 + (l&15)
  float psum[4] = {0.f, 0.f, 0.f, 0.f};
#pragma unroll
  for (int ni = 0; ni < 4; ++ni) {
    const int o = otile*256 + wc*64 + ni*16 + (l & 15);
    const float bqo = bq[o];
    const __bf16* klc = kl_t + (int64_t)o * 256 + wr*128 + (l >> 4)*4;
#pragma unroll
    for (int mi = 0; mi < 8; ++mi) {
      bf16x4 kv = *(const bf16x4*)(klc + mi*16);
      psum[ni] += (acc[mi][ni][0] + bqo) * (float)kv[0]
                + (acc[mi][ni][1] + bqo) * (float)kv[1]
                + (acc[mi][ni][2] + bqo) * (float)kv[2]
                + (acc[mi][ni][3] + bqo) * (float)kv[3];
    }
  }
#pragma unroll
  for (int ni = 0; ni < 4; ++ni) {  // reduce over the 4 row-groups (l>>4)
    psum[ni] += __shfl_xor(psum[ni], 16);
    psum[ni] += __shfl_xor(psum[ni], 32);
  }
  float* red = (float*)smem;  // [2][256] f32 (all LDS buffers dead by now)
  if (l < 16) {
#pragma unroll
    for (int ni = 0; ni < 4; ++ni)
      red[wr*256 + wc*64 + ni*16 + l] = psum[ni];
  }
  __syncthreads();
  if (t < 256) {
    const float s = 0.0625f * (red[t] + red[256 + t]);  // fact * S[b, otile*256+t]
    float m = s;
    m = fmaxf(m, __shfl_xor(m, 1));
    m = fmaxf(m, __shfl_xor(m, 2));
    m = fmaxf(m, __shfl_xor(m, 4));
    const float e = __expf(s - m);
    float sum = e;
    sum += __shfl_xor(sum, 1);
    sum += __shfl_xor(sum, 2);
    sum += __shfl_xor(sum, 4);
    out[(int64_t)b*2048 + otile*256 + t] = e / sum;
  }
}

extern "C" void kernel_launch(void* const* d_in, const int* in_sizes, int n_in,
                              void* d_out, int out_size, void* d_ws, size_t ws_size,
                              hipStream_t stream) {
  (void)in_sizes; (void)n_in; (void)out_size; (void)ws_size;
  const float* q  = (const float*)d_in[0];
  const float* k  = (const float*)d_in[1];
  const float* Wq = (const float*)d_in[2];
  const float* bq = (const float*)d_in[3];
  const float* Wk = (const float*)d_in[4];
  const float* bk = (const float*)d_in[5];
  float* out = (float*)d_out;
  char* ws = (char*)d_ws;
  void* q_t  = ws;                          // 256 MiB  q bf16 TRANSPOSED [b][c][h]
  void* wq_b = ws + 268435456;              // 8 MiB    Wq bf16
  void* wk_b = ws + 268435456 + 8388608;    // 8 MiB    Wk bf16
  void* k_b  = ws + 268435456 + 16777216;   // 1 MiB    k bf16
  void* kl_t = ws + 268435456 + 17825792;   // 1 MiB    kl_t bf16 [2048 o][256 c]

  convert_kernel<<<2048, 256, 0, stream>>>(q, Wq, Wk, k, q_t, wq_b, wk_b, k_b);
  kl_kernel<<<dim3(32, 4), 256, 0, stream>>>(k_b, wk_b, bk, kl_t);
  main_kernel<<<dim3(8, 256), 512, 0, stream>>>(q_t, wq_b, bq, kl_t, out);
}

// Round 3
// 655.694 us; speedup vs baseline: 1.0842x; 1.0272x over previous
//
#include <hip/hip_runtime.h>
#include <stdint.h>

// out[b, q, n] = softmax_n( fact * S[b, q*8+n] ),  S[b,o] = sum_c ql[c,b,o]*kl[c,o]
//   ql[c,b,o] = sum_h q[c,b,h]*Wq[o,h] + bq[o]
//   kl[c,o]   = sum_d k[c,d]*Wk[o,d] + bk[o]
// A=B=256, H=QD=2048, n=8, fact = 1/16.
//
// R3: (a) ONE barrier per K-tile, tile body is plain C++ (24 ds_read_b128 +
// 64 MFMA) so the compiler's fine-grained lgkmcnt interleaves LDS reads under
// MFMAs (R2's explicit lgkm(0)+sched_barrier lockstep serialized them:
// wall 5580 cyc vs 2484 MFMA + 2304 LDS). Counted vmcnt(4) fence per tile,
// A(kt+2) always in flight. (b) XCD-aware block swizzle: b % 8 == xcd, the
// 8 otiles of each b consecutive on one XCD -> q-panel fetched from HBM once
// (FETCH 1.09 GB -> ~0.3 GB).

typedef __attribute__((ext_vector_type(8))) __bf16 bf16x8;
typedef __attribute__((ext_vector_type(4))) __bf16 bf16x4;
typedef __attribute__((ext_vector_type(4))) float f32x4;

__device__ __forceinline__ void gload_lds16(const void* g, void* l) {
  __builtin_amdgcn_global_load_lds(
      (const __attribute__((address_space(1))) uint32_t*)g,
      (__attribute__((address_space(3))) uint32_t*)l, 16, 0, 0);
}

// ---------------- convert: q (f32, transpose to [b][c][h]), Wq, Wk, k -> bf16
__global__ void convert_kernel(const float* __restrict__ qin,
                               const float* __restrict__ Wq,
                               const float* __restrict__ Wk,
                               const float* __restrict__ kin,
                               void* __restrict__ q_t,
                               void* __restrict__ wq_b, void* __restrict__ wk_b,
                               void* __restrict__ k_b) {
  const int NQ0 = 33554432;  // q float4 quads (256*256*2048/4); 512 quads/row
  const int NQ1 = 1048576;   // Wq quads
  const int NQ2 = 1048576;   // Wk quads
  const int NQ3 = 131072;    // k quads
  const int TOT = NQ0 + NQ1 + NQ2 + NQ3;
  for (int i = blockIdx.x * blockDim.x + threadIdx.x; i < TOT;
       i += gridDim.x * blockDim.x) {
    if (i < NQ0) {
      // src quad i = ((c*256)+b)*512 + jq  ->  dst quad = ((b*256)+c)*512 + jq
      float4 v = ((const float4*)qin)[i];
      const int jq = i & 511;
      const int b  = (i >> 9) & 255;
      const int c  = i >> 17;
      bf16x4 o;
      o[0] = (__bf16)v.x; o[1] = (__bf16)v.y; o[2] = (__bf16)v.z; o[3] = (__bf16)v.w;
      ((bf16x4*)q_t)[(int64_t)(((b << 8) + c) << 9) + jq] = o;
    } else {
      const float4* src; bf16x4* dst; int j;
      if (i < NQ0+NQ1)              { src = (const float4*)Wq;  dst = (bf16x4*)wq_b; j = i - NQ0; }
      else if (i < NQ0+NQ1+NQ2)     { src = (const float4*)Wk;  dst = (bf16x4*)wk_b; j = i - NQ0 - NQ1; }
      else                          { src = (const float4*)kin; dst = (bf16x4*)k_b;  j = i - NQ0 - NQ1 - NQ2; }
      float4 v = src[j];
      bf16x4 o;
      o[0] = (__bf16)v.x; o[1] = (__bf16)v.y; o[2] = (__bf16)v.z; o[3] = (__bf16)v.w;
      dst[j] = o;
    }
  }
}

// ---------------- kl kernel: kl_t[o][c] = bf16(k . Wk^T + bk) ----------------
__global__ __launch_bounds__(256)
void kl_kernel(const void* __restrict__ k_b, const void* __restrict__ wk_b,
               const float* __restrict__ bk, void* __restrict__ kl_t_v) {
  __shared__ char smem[32768];  // 2 bufs x (A 8K + B 8K)
  const __bf16* kb   = (const __bf16*)k_b;
  const __bf16* wkb  = (const __bf16*)wk_b;
  __bf16* kl_t = (__bf16*)kl_t_v;
  const int t = threadIdx.x, w = t >> 6, l = t & 63;
  const int ntile = blockIdx.x, mtile = blockIdx.y;
  const int wr = w >> 1, wc = w & 1;
  f32x4 acc[2][2] = {};

  auto stage = [&](int buf, int kt) {
    const int row = t >> 3;
    const int col = (((t & 7) ^ (row & 7)) << 3);
#pragma unroll
    for (int i = 0; i < 2; ++i) {
      const __bf16* ga = kb + (int64_t)(mtile*64 + i*32 + row) * 2048 + kt*64 + col;
      gload_lds16(ga, smem + buf*16384 + (i*256 + w*64)*16);
      const __bf16* gb = wkb + (int64_t)(ntile*64 + i*32 + row) * 2048 + kt*64 + col;
      gload_lds16(gb, smem + buf*16384 + 8192 + (i*256 + w*64)*16);
    }
  };

  stage(0, 0);
  __syncthreads();
  int cur = 0;
  for (int kt = 0; kt < 32; ++kt) {
    if (kt + 1 < 32) stage(cur ^ 1, kt + 1);
    const char* bA = smem + cur*16384;
    const char* bB = smem + cur*16384 + 8192;
#pragma unroll
    for (int kq = 0; kq < 2; ++kq) {
      bf16x8 a[2], b[2];
      const int g = kq*4 + (l >> 4);
#pragma unroll
      for (int mi = 0; mi < 2; ++mi) {
        const int r = wr*32 + mi*16 + (l & 15);
        a[mi] = *(const bf16x8*)(bA + r*128 + ((g ^ (r & 7)) << 4));
      }
#pragma unroll
      for (int ni = 0; ni < 2; ++ni) {
        const int r = wc*32 + ni*16 + (l & 15);
        b[ni] = *(const bf16x8*)(bB + r*128 + ((g ^ (r & 7)) << 4));
      }
#pragma unroll
      for (int mi = 0; mi < 2; ++mi)
#pragma unroll
        for (int ni = 0; ni < 2; ++ni)
          acc[mi][ni] = __builtin_amdgcn_mfma_f32_16x16x32_bf16(a[mi], b[ni], acc[mi][ni], 0, 0, 0);
    }
    __syncthreads();
    cur ^= 1;
  }

#pragma unroll
  for (int ni = 0; ni < 2; ++ni) {
    const int o = ntile*64 + wc*32 + ni*16 + (l & 15);
    const float bko = bk[o];
#pragma unroll
    for (int mi = 0; mi < 2; ++mi) {
      const int c0 = mtile*64 + wr*32 + mi*16 + (l >> 4)*4;
      bf16x4 v;
      v[0] = (__bf16)(acc[mi][ni][0] + bko);
      v[1] = (__bf16)(acc[mi][ni][1] + bko);
      v[2] = (__bf16)(acc[mi][ni][2] + bko);
      v[3] = (__bf16)(acc[mi][ni][3] + bko);
      *(bf16x4*)(kl_t + (int64_t)o*256 + c0) = v;
    }
  }
}

// ---------------- main fused kernel: 1 barrier per K-tile, compiler-scheduled
// Per K-tile: issue stages (B(kt+1), A(kt+2)) early, then plain-C++ body:
// 24 ds_read_b128 + 64 MFMA (compiler interleaves via fine-grained lgkmcnt),
// then counted vmcnt(4) fence (A(kt+1)+B(kt+1) complete, A(kt+2) in flight)
// + ONE raw s_barrier. LDS: A 3 bufs x 32K, B 2 bufs x 32K = 160 KiB.
__global__ __launch_bounds__(512, 2)
void main_kernel(const void* __restrict__ q_tv, const void* __restrict__ wq_b,
                 const float* __restrict__ bq, const void* __restrict__ kl_t_v,
                 float* __restrict__ out) {
  __shared__ char smem[163840];  // A: 3x32K [0,96K); B: 2x32K [96K,160K)
  const __bf16* qt   = (const __bf16*)q_tv;   // [b][c][h] bf16
  const __bf16* wqb  = (const __bf16*)wq_b;
  const __bf16* kl_t = (const __bf16*)kl_t_v;
  const int t = threadIdx.x, w = t >> 6, l = t & 63;
  // XCD-aware swizzle: lid%8 == XCD hosts b with b%8 == xcd; the 8 otiles of
  // each b are consecutive slots on that XCD -> q-panel L2-reused 8x.
  const int lid = blockIdx.x + 8 * blockIdx.y;   // bijective remap, grid=2048
  const int xcd = lid & 7, slot = lid >> 3;
  const int otile = slot & 7;
  const int b = ((slot >> 3) << 3) | xcd;
  const int wr = w >> 2, wc = w & 3;
  f32x4 acc[8][4] = {};

  // stage A row-half of tile kt (rows half*64+[0,64) and 128+half*64+[0,64))
  auto stageA = [&](int buf, int kt, int half) {
#pragma unroll
    for (int i = 0; i < 2; ++i) {
      const int r = i*128 + half*64 + (t >> 3);
      const int sg = (t & 7) ^ (r & 7);
      const __bf16* ga = qt + (int64_t)(b*256 + r) * 2048 + kt*64 + sg*8;
      gload_lds16(ga, smem + buf*32768 + r*128 + (t & 7)*16);
    }
  };
  // stage B row-half of tile kt
  auto stageB = [&](int buf, int kt, int half) {
#pragma unroll
    for (int i = 0; i < 2; ++i) {
      const int row64 = t >> 3;
      const int r = i*128 + half*32 + (row64 & 31) + ((row64 >> 5) << 6);
      const int sg = (t & 7) ^ (r & 7);
      const __bf16* gb = wqb + (int64_t)(otile*256 + r) * 2048 + kt*64 + sg*8;
      gload_lds16(gb, smem + 98304 + buf*32768 + r*128 + (t & 7)*16);
    }
  };

  // full-tile compute: 24 ds_read_b128 + 64 MFMA, plain C++ (no asm pinning)
  auto compute = [&](int abuf, int bbuf) {
    const char* bA_ = smem + abuf*32768;
    const char* bB_ = smem + 98304 + bbuf*32768;
#pragma unroll
    for (int h = 0; h < 2; ++h) {
      const int g_ = h*4 + (l >> 4);
      bf16x8 af[8], bfr[4];
#pragma unroll
      for (int m2 = 0; m2 < 8; ++m2) {
        const int r_ = wr*128 + m2*16 + (l & 15);
        af[m2] = *(const bf16x8*)(bA_ + r_*128 + ((g_ ^ (r_ & 7)) << 4));
      }
#pragma unroll
      for (int n2 = 0; n2 < 4; ++n2) {
        const int r_ = wc*64 + n2*16 + (l & 15);
        bfr[n2] = *(const bf16x8*)(bB_ + r_*128 + ((g_ ^ (r_ & 7)) << 4));
      }
#pragma unroll
      for (int m2 = 0; m2 < 8; ++m2)
#pragma unroll
        for (int n2 = 0; n2 < 4; ++n2)
          acc[m2][n2] = __builtin_amdgcn_mfma_f32_16x16x32_bf16(
              af[m2], bfr[n2], acc[m2][n2], 0, 0, 0);
    }
  };

  // prologue: A(0), B(0) full + A(1) full; vmcnt(4) -> tile0 complete,
  // A(1) (4 loads) stays in flight == steady-state entry condition.
  stageA(0, 0, 0); stageA(0, 0, 1);
  stageB(0, 0, 0); stageB(0, 0, 1);
  stageA(1, 1, 0); stageA(1, 1, 1);
  asm volatile("s_waitcnt vmcnt(4)" ::: "memory");
  __builtin_amdgcn_s_barrier();

  int ac = 0;  // A-buf holding tile kt (= kt % 3)
  for (int kt = 0; kt < 32; ++kt) {
    const int as = (ac >= 1) ? ac - 1 : 2;  // (kt+2) % 3
    const int bc = kt & 1, bs = bc ^ 1;
    // issue next-tile stages first (vmem latency hides under compute)
    if (kt < 31) { stageB(bs, kt + 1, 0); stageB(bs, kt + 1, 1); }
    if (kt < 30) { stageA(as, kt + 2, 0); stageA(as, kt + 2, 1); }
    compute(ac, bc);
    // fence: oldest 8 in flight = A(kt+1)+B(kt+1); keep A(kt+2) in flight
    if (kt < 30)      { asm volatile("s_waitcnt vmcnt(4)" ::: "memory"); }
    else if (kt < 31) { asm volatile("s_waitcnt vmcnt(0)" ::: "memory"); }
    __builtin_amdgcn_s_barrier();
    ac = (ac == 2) ? 0 : ac + 1;
  }

  // ---- epilogue ----
  // C/D frag layout: row(c) = wr*128 + mi*16 + (l>>4)*4 + reg, col(o) = wc*64 + ni*16 + (l&15)
  float psum[4] = {0.f, 0.f, 0.f, 0.f};
#pragma unroll
  for (int ni = 0; ni < 4; ++ni) {
    const int o = otile*256 + wc*64 + ni*16 + (l & 15);
    const float bqo = bq[o];
    const __bf16* klc = kl_t + (int64_t)o * 256 + wr*128 + (l >> 4)*4;
#pragma unroll
    for (int mi = 0; mi < 8; ++mi) {
      bf16x4 kv = *(const bf16x4*)(klc + mi*16);
      psum[ni] += (acc[mi][ni][0] + bqo) * (float)kv[0]
                + (acc[mi][ni][1] + bqo) * (float)kv[1]
                + (acc[mi][ni][2] + bqo) * (float)kv[2]
                + (acc[mi][ni][3] + bqo) * (float)kv[3];
    }
  }
#pragma unroll
  for (int ni = 0; ni < 4; ++ni) {  // reduce over the 4 row-groups (l>>4)
    psum[ni] += __shfl_xor(psum[ni], 16);
    psum[ni] += __shfl_xor(psum[ni], 32);
  }
  float* red = (float*)smem;  // [2][256] f32 (A buf 0 dead for reads by now)
  if (l < 16) {
#pragma unroll
    for (int ni = 0; ni < 4; ++ni)
      red[wr*256 + wc*64 + ni*16 + l] = psum[ni];
  }
  __syncthreads();
  if (t < 256) {
    const float s = 0.0625f * (red[t] + red[256 + t]);  // fact * S[b, otile*256+t]
    float m = s;
    m = fmaxf(m, __shfl_xor(m, 1));
    m = fmaxf(m, __shfl_xor(m, 2));
    m = fmaxf(m, __shfl_xor(m, 4));
    const float e = __expf(s - m);
    float sum = e;
    sum += __shfl_xor(sum, 1);
    sum += __shfl_xor(sum, 2);
    sum += __shfl_xor(sum, 4);
    out[(int64_t)b*2048 + otile*256 + t] = e / sum;
  }
}

extern "C" void kernel_launch(void* const* d_in, const int* in_sizes, int n_in,
                              void* d_out, int out_size, void* d_ws, size_t ws_size,
                              hipStream_t stream) {
  (void)in_sizes; (void)n_in; (void)out_size; (void)ws_size;
  const float* q  = (const float*)d_in[0];
  const float* k  = (const float*)d_in[1];
  const float* Wq = (const float*)d_in[2];
  const float* bq = (const float*)d_in[3];
  const float* Wk = (const float*)d_in[4];
  const float* bk = (const float*)d_in[5];
  float* out = (float*)d_out;
  char* ws = (char*)d_ws;
  void* q_t  = ws;                          // 256 MiB  q bf16 TRANSPOSED [b][c][h]
  void* wq_b = ws + 268435456;              // 8 MiB    Wq bf16
  void* wk_b = ws + 268435456 + 8388608;    // 8 MiB    Wk bf16
  void* k_b  = ws + 268435456 + 16777216;   // 1 MiB    k bf16
  void* kl_t = ws + 268435456 + 17825792;   // 1 MiB    kl_t bf16 [2048 o][256 c]

  convert_kernel<<<2048, 256, 0, stream>>>(q, Wq, Wk, k, q_t, wq_b, wk_b, k_b);
  kl_kernel<<<dim3(32, 4), 256, 0, stream>>>(k_b, wk_b, bk, kl_t);
  main_kernel<<<dim3(8, 256), 512, 0, stream>>>(q_t, wq_b, bq, kl_t, out);
}